// Round 3
// baseline (28.394 us; speedup 1.0000x reference)
//
#include <hip/hip_runtime.h>

// FastGuidedFilter on MI355X — round 9: wave-autonomous, zero barriers.
// Round-8 post-mortem: 24->32 waves/CU bought only 3% (TLP exhausted); all
// throughput resources (VALU ~6.5us, LDS ~5us, HBM writes ~10us overlapped,
// L3 reads ~75MB) sit far below the 26.4us measured -> intra-block
// serialization is the remaining cost: 2x __syncthreads lockstep 4 waves,
// and hr-first load order forces vmcnt(0) drain before phase A.
// This round:
//   * Each WAVE owns 64 px x 5 rows (1920 = 30*64 exact, no valid masks).
//     Footprint/wave: 3 rowsets x 20 vs-cols (60 tasks), 3 x 18 A-cols (54).
//   * Per-wave private LDS region (240 float4 = 3840 B), A/b overlaid on the
//     dead vs buffer -> ZERO __syncthreads. Same-wave ds_write->ds_read is
//     ordered by the in-order per-wave DS pipe; aliasing keeps the compiler
//     from reordering; wave_barrier() as scheduling insurance.
//   * lr loads issued BEFORE hr loads: phase A runs at vmcnt(5) while the
//     5 hr loads stay outstanding until phase C (true prefetch).
//   * LDS 15360 B/block, 4 waves/block, grid 3240 blocks; 8 blocks/CU
//     (wave cap) if VGPR <= 64 — verify VGPR_Count next round.
//
// Shapes (NHWC, C=4 => one float4 per pixel):
//   lr_x, lr_y : (2, 270, 480, 4) f32
//   hr_x       : (2, 1080, 1920, 4) f32
//   out        : (2, 1080, 1920, 4) f32

namespace {

constexpr int LR_H = 270, LR_W = 480;
constexpr int A_H  = 268, A_W  = 478;   // VALID 3x3 output grid
constexpr int HR_H = 1080, HR_W = 1920;
constexpr int BATCH = 2;
constexpr float EPS_F = 1e-5f;

constexpr int WTILE = 64;                 // HR px per wave (exact: 30 waves/row)
constexpr int NWT   = HR_W / WTILE;       // 30
constexpr int ROWS  = 5;                  // HR rows per wave
constexpr int ROWGRP = HR_H / ROWS;       // 216, exact
constexpr int RSETS = 3;                  // A-rowsets (vertical tent t in [0,2))
constexpr int WVC   = 20;  // vs cols/wave: 16 px-span + 1 lerp nbr + 2 taps (+pad)
constexpr int WAC   = 18;  // A/b cols/wave (wi <= 16, +1 neighbor)
constexpr int WSLOT = RSETS * 4 * WVC;    // 240 float4 per wave region

using f32x4 = __attribute__((ext_vector_type(4))) float;

__device__ __forceinline__ float4 f4add(float4 a, float4 b) {
    return make_float4(a.x + b.x, a.y + b.y, a.z + b.z, a.w + b.w);
}
__device__ __forceinline__ float4 f4sub(float4 a, float4 b) {
    return make_float4(a.x - b.x, a.y - b.y, a.z - b.z, a.w - b.w);
}
__device__ __forceinline__ float4 f4mul(float4 a, float4 b) {
    return make_float4(a.x * b.x, a.y * b.y, a.z * b.z, a.w * b.w);
}
__device__ __forceinline__ float4 f4scale(float4 a, float s) {
    return make_float4(a.x * s, a.y * s, a.z * s, a.w * s);
}
__device__ __forceinline__ float4 f4fma(float4 a, float4 b, float4 c) {
    return make_float4(fmaf(a.x, b.x, c.x), fmaf(a.y, b.y, c.y),
                       fmaf(a.z, b.z, c.z), fmaf(a.w, b.w, c.w));
}
__device__ __forceinline__ float4 f4lerp(float4 a, float4 b, float t) {
    return make_float4(fmaf(t, b.x - a.x, a.x), fmaf(t, b.y - a.y, a.y),
                       fmaf(t, b.z - a.z, a.z), fmaf(t, b.w - a.w, a.w));
}
// acc += s * v (scalar s)
__device__ __forceinline__ float4 f4axpy(float s, float4 v, float4 acc) {
    return make_float4(fmaf(s, v.x, acc.x), fmaf(s, v.y, acc.y),
                       fmaf(s, v.z, acc.z), fmaf(s, v.w, acc.w));
}
__device__ __forceinline__ float4 f4rcp(float4 a) {
    return make_float4(__builtin_amdgcn_rcpf(a.x), __builtin_amdgcn_rcpf(a.y),
                       __builtin_amdgcn_rcpf(a.z), __builtin_amdgcn_rcpf(a.w));
}
__device__ __forceinline__ void nt_store(float4 v, float4* p) {
    f32x4 rv = {v.x, v.y, v.z, v.w};
    __builtin_nontemporal_store(rv, (f32x4*)p);
}

} // namespace

__global__ __launch_bounds__(256) void
fgf_wave(const float4* __restrict__ lr_x,
         const float4* __restrict__ lr_y,
         const float4* __restrict__ hr_x,
         float4* __restrict__ out) {
    // Per-wave private region: vs[3 rs][4 q][20 cs] (slots 0..239), later
    // overlaid by ab[3 rs][2 f][18 sl] (slots 0..107) once vs is dead.
    __shared__ float4 smem[4][WSLOT];     // 15360 B

    int tid  = threadIdx.x;
    int wid  = tid >> 6;
    int lane = tid & 63;
    int widx = blockIdx.x * 4 + wid;      // global wave index, 0..12959

    int wt = widx % NWT;                  // wave-tile column 0..29
    int g  = widx / NWT;
    int rg = g % ROWGRP;                  // row group 0..215
    int b  = g / ROWGRP;                  // batch 0..1

    // jax.image.resize bilinear (antialias=False): src = (i+0.5)*in/out - 0.5,
    // edge renormalization == index-clamped bilinear.
    constexpr float sh_scale = (float)A_H / (float)HR_H;   // 0.248148
    constexpr float sw_scale = (float)A_W / (float)HR_W;   // 0.248958

    int hbase = rg * ROWS;
    int R0 = (int)floorf((hbase + 0.5f) * sh_scale - 0.5f); // -1 at top edge

    int w0px = wt * WTILE;
    int c0 = (int)floorf((w0px + 0.5f) * sw_scale - 0.5f);  // -1 at left edge

    float4* vs = &smem[wid][0];

    // ---- Phase A addressing + lr loads, issued FIRST (oldest in vmcnt):
    // phase A's sums then need only vmcnt(5), leaving hr loads in flight.
    // Lanes 60..63 clamp to task 59 (duplicate loads/stores, same data).
    int t = min(lane, RSETS * WVC - 1);
    int rs = t / WVC;
    int cs = t - rs * WVC;
    int ar  = min(max(R0 + rs, 0), A_H - 1);       // lr top row of 3-tap
    int col = min(max(c0 + cs, 0), LR_W - 1);      // lr col (clamped)
    const float4* px = lr_x + ((size_t)b * LR_H + ar) * LR_W + col;
    const float4* py = lr_y + ((size_t)b * LR_H + ar) * LR_W + col;
    float4 x0 = px[0], x1 = px[LR_W], x2 = px[2 * LR_W];
    float4 y0 = py[0], y1 = py[LR_W], y2 = py[2 * LR_W];

    // ---- hr prefetch (consumed only in phase C; stays outstanding).
    int w = w0px + lane;                            // always < HR_W (exact tiling)
    size_t hr0 = ((size_t)b * HR_H + hbase) * (size_t)HR_W + w;
    float4 xr[ROWS];
#pragma unroll
    for (int j = 0; j < ROWS; ++j) {
        xr[j] = hr_x[hr0 + (size_t)j * HR_W];
    }

    // ---- Phase A: vertical 3-tap sums -> per-wave LDS.
    float4 sx  = f4add(f4add(x0, x1), x2);
    float4 sy  = f4add(f4add(y0, y1), y2);
    float4 sxy = f4fma(x0, y0, f4fma(x1, y1, f4mul(x2, y2)));
    float4 sxx = f4fma(x0, x0, f4fma(x1, x1, f4mul(x2, x2)));
    vs[rs * (4 * WVC) + 0 * WVC + cs] = sx;
    vs[rs * (4 * WVC) + 1 * WVC + cs] = sy;
    vs[rs * (4 * WVC) + 2 * WVC + cs] = sxy;
    vs[rs * (4 * WVC) + 3 * WVC + cs] = sxx;
    __builtin_amdgcn_wave_barrier();   // scheduling fence (no inst); DS pipe
                                       // is in-order per wave -> reads below
                                       // see the writes above.

    // ---- Phase B: horizontal 3-tap -> A,b; write into overlay (vs is dead
    // after these reads; in-wave program order makes the overlay safe).
    constexpr float inv9 = 1.0f / 9.0f;
    int t2  = min(lane, RSETS * WAC - 1);
    int rs2 = t2 / WAC;
    int sl  = t2 - rs2 * WAC;
    int a   = min(max(c0 + sl, 0), A_W - 1);   // A-col this slot represents
    int bs  = a - c0;                          // vs slots bs..bs+2 = cols a..a+2
    const float4* vb = vs + rs2 * (4 * WVC) + bs;
    float4 hx  = f4add(f4add(vb[0],       vb[1]),           vb[2]);
    float4 hy  = f4add(f4add(vb[WVC],     vb[WVC + 1]),     vb[WVC + 2]);
    float4 hxy = f4add(f4add(vb[2 * WVC], vb[2 * WVC + 1]), vb[2 * WVC + 2]);
    float4 hxx = f4add(f4add(vb[3 * WVC], vb[3 * WVC + 1]), vb[3 * WVC + 2]);
    float4 mx  = f4scale(hx, inv9);
    float4 my  = f4scale(hy, inv9);
    float4 cov = f4sub(f4scale(hxy, inv9), f4mul(mx, my));
    float4 var = f4sub(f4scale(hxx, inv9), f4mul(mx, mx));
    float4 A = f4mul(cov, f4rcp(make_float4(var.x + EPS_F, var.y + EPS_F,
                                            var.z + EPS_F, var.w + EPS_F)));
    float4 bb = f4sub(my, f4mul(A, mx));
    __builtin_amdgcn_wave_barrier();
    vs[(rs2 * 2 + 0) * WAC + sl] = A;      // overlay slots 0..107
    vs[(rs2 * 2 + 1) * WAC + sl] = bb;
    __builtin_amdgcn_wave_barrier();

    // ---- Phase C: horizontal lerp (row-invariant) + vertical tent + fma.
    float swf = (w + 0.5f) * sw_scale - 0.5f;
    float fw = floorf(swf);
    float tw = swf - fw;
    int wi = (int)fw - c0;                 // 0..16; wi+1 <= 17 = WAC-1

    float4 hA0 = f4lerp(vs[0 * WAC + wi], vs[0 * WAC + wi + 1], tw);
    float4 hB0 = f4lerp(vs[1 * WAC + wi], vs[1 * WAC + wi + 1], tw);
    float4 hA1 = f4lerp(vs[2 * WAC + wi], vs[2 * WAC + wi + 1], tw);
    float4 hB1 = f4lerp(vs[3 * WAC + wi], vs[3 * WAC + wi + 1], tw);
    float4 hA2 = f4lerp(vs[4 * WAC + wi], vs[4 * WAC + wi + 1], tw);
    float4 hB2 = f4lerp(vs[5 * WAC + wi], vs[5 * WAC + wi + 1], tw);

#pragma unroll
    for (int j = 0; j < ROWS; ++j) {
        // t in [0,2): tent weights over the 3 staged rowsets reproduce the
        // clamped vertical lerp exactly (slots hold clamped rows).
        float shj = (hbase + j + 0.5f) * sh_scale - 0.5f;
        float tv = shj - (float)R0;
        float w0 = fmaxf(1.f - tv, 0.f);
        float w1 = 1.f - fabsf(tv - 1.f);
        float w2 = fmaxf(tv - 1.f, 0.f);

        float4 aI = f4axpy(w2, hA2, f4axpy(w1, hA1, f4scale(hA0, w0)));
        float4 bI = f4axpy(w2, hB2, f4axpy(w1, hB1, f4scale(hB0, w0)));

        nt_store(f4fma(aI, xr[j], bI), &out[hr0 + (size_t)j * HR_W]);
    }
}

extern "C" void kernel_launch(void* const* d_in, const int* in_sizes, int n_in,
                              void* d_out, int out_size, void* d_ws, size_t ws_size,
                              hipStream_t stream) {
    const float4* lr_x = (const float4*)d_in[0];
    const float4* lr_y = (const float4*)d_in[1];
    const float4* hr_x = (const float4*)d_in[2];
    float4* out = (float4*)d_out;

    constexpr int nblocks = BATCH * ROWGRP * NWT / 4;   // 12960/4 = 3240
    fgf_wave<<<nblocks, 256, 0, stream>>>(lr_x, lr_y, hr_x, out);
}

// Round 4
// 27.488 us; speedup vs baseline: 1.0330x; 1.0330x over previous
//
#include <hip/hip_runtime.h>

// FastGuidedFilter on MI355X — round 10: 2 row-group tasks per block.
// Round-9 post-mortem (FAILED 28.4us): wave-autonomy added 33% lr traffic +
// duplicated phase-B work; barriers were never the cost. Round-8 analysis:
// block lifetime ~15.6us vs ~1.5us of work — waves queue on memory, HBM
// writes run at 2.5 TB/s vs 6.7 demonstrated, because each block's 5 stores
// burst at end-of-life followed by the pre-endpgm drain, serialized into
// block turnover. This round (round-8 structure retained):
//   * Each block runs TWO consecutive row-groups (same tile column) in
//     sequence. Iter-1's nt-stores stay outstanding while iter-2 loads and
//     computes -> write stream overlaps next task's reads; 1728 drains
//     instead of 3456. Barrier safety: iter-2 phase-A vs-writes sit after
//     iter-1 barrier-2; iter-2 sA4-writes after iter-2 barrier-1.
//   * lr loads issued BEFORE hr loads (branchless clamped task id): phase A
//     consumes lr at vmcnt(5), hr loads stay in flight through A/B.
//
// Shapes (NHWC, C=4 => one float4 per pixel):
//   lr_x, lr_y : (2, 270, 480, 4) f32
//   hr_x       : (2, 1080, 1920, 4) f32
//   out        : (2, 1080, 1920, 4) f32

namespace {

constexpr int LR_H = 270, LR_W = 480;
constexpr int A_H  = 268, A_W  = 478;   // VALID 3x3 output grid
constexpr int HR_H = 1080, HR_W = 1920;
constexpr int BATCH = 2;
constexpr float EPS_F = 1e-5f;

constexpr int TILE_W = 240;                 // HR px per block row (1920/240=8 exact)
constexpr int NTILES = HR_W / TILE_W;       // 8, uniform
constexpr int ROWS   = 5;                   // HR rows per iteration
constexpr int ITERS  = 2;                   // row-groups per block
constexpr int ROWGRP = HR_H / ROWS;         // 216, exact
constexpr int NPAIR  = ROWGRP / ITERS;      // 108
constexpr int VCOLS  = 64;   // vertical-sum slots (A-cols + 2 taps); power of 2
constexpr int ACOLS  = 62;   // A/b slots (max wi = 60, +1 neighbor)
constexpr int RSETS  = 3;    // A-rowsets staged (5 rows: tent t in [0,2))

using f32x4 = __attribute__((ext_vector_type(4))) float;

__device__ __forceinline__ float4 f4add(float4 a, float4 b) {
    return make_float4(a.x + b.x, a.y + b.y, a.z + b.z, a.w + b.w);
}
__device__ __forceinline__ float4 f4sub(float4 a, float4 b) {
    return make_float4(a.x - b.x, a.y - b.y, a.z - b.z, a.w - b.w);
}
__device__ __forceinline__ float4 f4mul(float4 a, float4 b) {
    return make_float4(a.x * b.x, a.y * b.y, a.z * b.z, a.w * b.w);
}
__device__ __forceinline__ float4 f4scale(float4 a, float s) {
    return make_float4(a.x * s, a.y * s, a.z * s, a.w * s);
}
__device__ __forceinline__ float4 f4fma(float4 a, float4 b, float4 c) {
    return make_float4(fmaf(a.x, b.x, c.x), fmaf(a.y, b.y, c.y),
                       fmaf(a.z, b.z, c.z), fmaf(a.w, b.w, c.w));
}
__device__ __forceinline__ float4 f4lerp(float4 a, float4 b, float t) {
    return make_float4(fmaf(t, b.x - a.x, a.x), fmaf(t, b.y - a.y, a.y),
                       fmaf(t, b.z - a.z, a.z), fmaf(t, b.w - a.w, a.w));
}
// acc += s * v (scalar s)
__device__ __forceinline__ float4 f4axpy(float s, float4 v, float4 acc) {
    return make_float4(fmaf(s, v.x, acc.x), fmaf(s, v.y, acc.y),
                       fmaf(s, v.z, acc.z), fmaf(s, v.w, acc.w));
}
__device__ __forceinline__ float4 f4rcp(float4 a) {
    return make_float4(__builtin_amdgcn_rcpf(a.x), __builtin_amdgcn_rcpf(a.y),
                       __builtin_amdgcn_rcpf(a.z), __builtin_amdgcn_rcpf(a.w));
}
__device__ __forceinline__ void nt_store(float4 v, float4* p) {
    f32x4 rv = {v.x, v.y, v.z, v.w};
    __builtin_nontemporal_store(rv, (f32x4*)p);
}

} // namespace

__global__ __launch_bounds__(256) void
fgf_fused5p(const float4* __restrict__ lr_x,
            const float4* __restrict__ lr_y,
            const float4* __restrict__ hr_x,
            float4* __restrict__ out) {
    // [rowset][quantity x,y,xy,xx][col] — column-contiguous => conflict-free
    __shared__ float4 vs[RSETS][4][VCOLS];       // 12288 B
    __shared__ float4 sA4[RSETS][ACOLS];         //  2976 B
    __shared__ float4 sB4[RSETS][ACOLS];         //  2976 B => 18240 B total

    int bid  = blockIdx.x;
    int tile = bid & (NTILES - 1);   // NTILES = 8
    int q    = bid >> 3;
    int pr   = q % NPAIR;
    int b    = q / NPAIR;
    int tid  = threadIdx.x;

    // jax.image.resize bilinear (antialias=False): src = (i+0.5)*in/out - 0.5,
    // edge renormalization == index-clamped bilinear.
    constexpr float sh_scale = (float)A_H / (float)HR_H;   // 0.248148
    constexpr float sw_scale = (float)A_W / (float)HR_W;   // 0.248958

    int w_start = tile * TILE_W;
    int c0 = (int)floorf((w_start + 0.5f) * sw_scale - 0.5f); // -1 at left edge

    int w = w_start + tid;
    bool valid = (tid < TILE_W);

    // ---- Iteration-invariant task decodes.
    // Phase A (branchless clamp: lanes 192..255 duplicate task 191's loads).
    int tA  = min(tid, RSETS * VCOLS - 1);
    int rsA = tA >> 6;                             // VCOLS = 64
    int csA = tA & 63;
    int colA = min(max(c0 + csA, 0), LR_W - 1);    // lr col (clamped)
    // Phase B: wave rsB handles rowset rsB, lanes 0..ACOLS-1.
    int rsB = tid >> 6;
    int slB = tid & 63;
    bool bAct = (rsB < RSETS) && (slB < ACOLS);
    int aB  = min(max(c0 + slB, 0), A_W - 1);      // A-col this slot represents
    int bsB = aB - c0;                             // vs slots bsB..bsB+2 = cols aB..aB+2
    // Phase C horizontal invariants.
    float swf = (w + 0.5f) * sw_scale - 0.5f;
    float fwf = floorf(swf);
    float tw  = swf - fwf;
    int wi = min((int)fwf - c0, ACOLS - 2);        // 0..60 for valid lanes

    constexpr float inv9 = 1.0f / 9.0f;

#pragma unroll 1
    for (int it = 0; it < ITERS; ++it) {
        int rg = pr * ITERS + it;
        int hbase = rg * ROWS;
        int R0 = (int)floorf((hbase + 0.5f) * sh_scale - 0.5f); // -1 at top edge
        size_t hr0 = ((size_t)b * HR_H + hbase) * (size_t)HR_W + w;

        // ---- lr loads FIRST (oldest in vmcnt): phase A then waits only
        // vmcnt(5), leaving the 5 hr loads below in flight through A/B.
        int ar = min(max(R0 + rsA, 0), A_H - 1);   // lr top row of 3-tap
        const float4* px = lr_x + ((size_t)b * LR_H + ar) * LR_W + colA;
        const float4* py = lr_y + ((size_t)b * LR_H + ar) * LR_W + colA;
        float4 x0 = px[0], x1 = px[(size_t)LR_W], x2 = px[(size_t)(2 * LR_W)];
        float4 y0 = py[0], y1 = py[(size_t)LR_W], y2 = py[(size_t)(2 * LR_W)];

        // ---- hr loads second (consumed only in phase C).
        float4 xr[ROWS];
#pragma unroll
        for (int j = 0; j < ROWS; ++j) {
            xr[j] = valid ? hr_x[hr0 + (size_t)j * HR_W]
                          : make_float4(0.f, 0.f, 0.f, 0.f);
        }

        // ---- Phase A: vertical 3-tap sums -> LDS.
        float4 sx  = f4add(f4add(x0, x1), x2);
        float4 sy  = f4add(f4add(y0, y1), y2);
        float4 sxy = f4fma(x0, y0, f4fma(x1, y1, f4mul(x2, y2)));
        float4 sxx = f4fma(x0, x0, f4fma(x1, x1, f4mul(x2, x2)));
        if (tid < RSETS * VCOLS) {
            vs[rsA][0][csA] = sx;
            vs[rsA][1][csA] = sy;
            vs[rsA][2][csA] = sxy;
            vs[rsA][3][csA] = sxx;
        }
        __syncthreads();

        // ---- Phase B: horizontal 3-tap -> A,b per rowset.
        if (bAct) {
            float4 hx  = f4add(f4add(vs[rsB][0][bsB], vs[rsB][0][bsB + 1]), vs[rsB][0][bsB + 2]);
            float4 hy  = f4add(f4add(vs[rsB][1][bsB], vs[rsB][1][bsB + 1]), vs[rsB][1][bsB + 2]);
            float4 hxy = f4add(f4add(vs[rsB][2][bsB], vs[rsB][2][bsB + 1]), vs[rsB][2][bsB + 2]);
            float4 hxx = f4add(f4add(vs[rsB][3][bsB], vs[rsB][3][bsB + 1]), vs[rsB][3][bsB + 2]);
            float4 mx  = f4scale(hx, inv9);
            float4 my  = f4scale(hy, inv9);
            float4 cov = f4sub(f4scale(hxy, inv9), f4mul(mx, my));
            float4 var = f4sub(f4scale(hxx, inv9), f4mul(mx, mx));
            float4 A = f4mul(cov, f4rcp(make_float4(var.x + EPS_F, var.y + EPS_F,
                                                    var.z + EPS_F, var.w + EPS_F)));
            float4 bb = f4sub(my, f4mul(A, mx));
            sA4[rsB][slB] = A;
            sB4[rsB][slB] = bb;
        }
        __syncthreads();

        // ---- Phase C: horizontal lerp (row-invariant) + vertical tent + fma.
        // NOTE: next iteration's phase-A vs-writes are safe (they precede the
        // next barrier-1, and sA4/sB4 rewrites precede nothing until after it).
        if (valid) {
            float4 hA0 = f4lerp(sA4[0][wi], sA4[0][wi + 1], tw);
            float4 hB0 = f4lerp(sB4[0][wi], sB4[0][wi + 1], tw);
            float4 hA1 = f4lerp(sA4[1][wi], sA4[1][wi + 1], tw);
            float4 hB1 = f4lerp(sB4[1][wi], sB4[1][wi + 1], tw);
            float4 hA2 = f4lerp(sA4[2][wi], sA4[2][wi + 1], tw);
            float4 hB2 = f4lerp(sB4[2][wi], sB4[2][wi + 1], tw);

#pragma unroll
            for (int j = 0; j < ROWS; ++j) {
                // t in [0,2): tent weights over the 3 staged rowsets reproduce
                // the clamped vertical lerp exactly (slots hold clamped rows).
                float shj = (hbase + j + 0.5f) * sh_scale - 0.5f;
                float tv = shj - (float)R0;
                float w0 = fmaxf(1.f - tv, 0.f);
                float w1 = 1.f - fabsf(tv - 1.f);
                float w2 = fmaxf(tv - 1.f, 0.f);

                float4 aI = f4axpy(w2, hA2, f4axpy(w1, hA1, f4scale(hA0, w0)));
                float4 bI = f4axpy(w2, hB2, f4axpy(w1, hB1, f4scale(hB0, w0)));

                nt_store(f4fma(aI, xr[j], bI), &out[hr0 + (size_t)j * HR_W]);
            }
        }
    }
}

extern "C" void kernel_launch(void* const* d_in, const int* in_sizes, int n_in,
                              void* d_out, int out_size, void* d_ws, size_t ws_size,
                              hipStream_t stream) {
    const float4* lr_x = (const float4*)d_in[0];
    const float4* lr_y = (const float4*)d_in[1];
    const float4* hr_x = (const float4*)d_in[2];
    float4* out = (float4*)d_out;

    constexpr int nblocks = BATCH * NPAIR * NTILES;   // 2 * 108 * 8 = 1728
    fgf_fused5p<<<nblocks, 256, 0, stream>>>(lr_x, lr_y, hr_x, out);
}

// Round 5
// 26.501 us; speedup vs baseline: 1.0715x; 1.0373x over previous
//
#include <hip/hip_runtime.h>

// FastGuidedFilter on MI355X — round 11: round-8 kernel, CACHED stores (A/B vs nt).
// Rounds 6-10 pattern: three different structures all land 26.4-27.5us —
// occupancy/barriers/granularity each move <=3% -> shared floor. The one
// untested assumption is the `nt` store flag (bundled into round 6, never
// isolated). Working set hr(66)+out(66)+lr(8) = 140 MB < 256 MB L3, so
// caching `out` evicts nothing that matters; `nt` forces the store path to
// the HBM-absorb rate and makes the end-of-block drain wait on HBM-depth
// queues. Cached stores complete at L3 speed; dirty write-back to HBM is
// asynchronous, off the kernel's critical path. Single change: nt -> plain.
//   Phase A: 3 rowsets x 64 cols vertical 3-tap sums {x,y,xy,xx} -> LDS
//   Phase B: 3 rowsets x 62 cols horizontal 3-tap -> (A,b) -> LDS
//   Phase C: hoisted horizontal lerp -> 3 (A,b) pairs/thread, then per row
//            3-slot tent-weight vertical combine + A*hr + b.
// hr_x loads issued before phases A/B (issue-early).
//
// Shapes (NHWC, C=4 => one float4 per pixel):
//   lr_x, lr_y : (2, 270, 480, 4) f32
//   hr_x       : (2, 1080, 1920, 4) f32
//   out        : (2, 1080, 1920, 4) f32

namespace {

constexpr int LR_H = 270, LR_W = 480;
constexpr int A_H  = 268, A_W  = 478;   // VALID 3x3 output grid
constexpr int HR_H = 1080, HR_W = 1920;
constexpr int BATCH = 2;
constexpr float EPS_F = 1e-5f;

constexpr int TILE_W = 240;                 // HR px per block row (1920/240=8 exact)
constexpr int NTILES = HR_W / TILE_W;       // 8, uniform
constexpr int ROWS   = 5;                   // HR rows per block
constexpr int ROWGRP = HR_H / ROWS;         // 216, exact
constexpr int VCOLS  = 64;   // vertical-sum slots (A-cols + 2 taps); power of 2
constexpr int ACOLS  = 62;   // A/b slots (max wi = 60, +1 neighbor)
constexpr int RSETS  = 3;    // A-rowsets staged (5 rows: tent t in [0,2))

__device__ __forceinline__ float4 f4add(float4 a, float4 b) {
    return make_float4(a.x + b.x, a.y + b.y, a.z + b.z, a.w + b.w);
}
__device__ __forceinline__ float4 f4sub(float4 a, float4 b) {
    return make_float4(a.x - b.x, a.y - b.y, a.z - b.z, a.w - b.w);
}
__device__ __forceinline__ float4 f4mul(float4 a, float4 b) {
    return make_float4(a.x * b.x, a.y * b.y, a.z * b.z, a.w * b.w);
}
__device__ __forceinline__ float4 f4scale(float4 a, float s) {
    return make_float4(a.x * s, a.y * s, a.z * s, a.w * s);
}
__device__ __forceinline__ float4 f4fma(float4 a, float4 b, float4 c) {
    return make_float4(fmaf(a.x, b.x, c.x), fmaf(a.y, b.y, c.y),
                       fmaf(a.z, b.z, c.z), fmaf(a.w, b.w, c.w));
}
__device__ __forceinline__ float4 f4lerp(float4 a, float4 b, float t) {
    return make_float4(fmaf(t, b.x - a.x, a.x), fmaf(t, b.y - a.y, a.y),
                       fmaf(t, b.z - a.z, a.z), fmaf(t, b.w - a.w, a.w));
}
// acc += s * v (scalar s)
__device__ __forceinline__ float4 f4axpy(float s, float4 v, float4 acc) {
    return make_float4(fmaf(s, v.x, acc.x), fmaf(s, v.y, acc.y),
                       fmaf(s, v.z, acc.z), fmaf(s, v.w, acc.w));
}
__device__ __forceinline__ float4 f4rcp(float4 a) {
    return make_float4(__builtin_amdgcn_rcpf(a.x), __builtin_amdgcn_rcpf(a.y),
                       __builtin_amdgcn_rcpf(a.z), __builtin_amdgcn_rcpf(a.w));
}

} // namespace

__global__ __launch_bounds__(256) void
fgf_fused5(const float4* __restrict__ lr_x,
           const float4* __restrict__ lr_y,
           const float4* __restrict__ hr_x,
           float4* __restrict__ out) {
    // [rowset][quantity x,y,xy,xx][col] — column-contiguous => conflict-free
    __shared__ float4 vs[RSETS][4][VCOLS];       // 12288 B
    __shared__ float4 sA4[RSETS][ACOLS];         //  2976 B
    __shared__ float4 sB4[RSETS][ACOLS];         //  2976 B => 18240 B total

    int bid  = blockIdx.x;
    int tile = bid & (NTILES - 1);   // NTILES = 8
    int g    = bid >> 3;
    int rg   = g % ROWGRP;
    int b    = g / ROWGRP;
    int tid  = threadIdx.x;

    // jax.image.resize bilinear (antialias=False): src = (i+0.5)*in/out - 0.5,
    // edge renormalization == index-clamped bilinear.
    constexpr float sh_scale = (float)A_H / (float)HR_H;   // 0.248148
    constexpr float sw_scale = (float)A_W / (float)HR_W;   // 0.248958

    int hbase = rg * ROWS;
    int R0 = (int)floorf((hbase + 0.5f) * sh_scale - 0.5f); // -1 at top edge

    int w_start = tile * TILE_W;
    int c0 = (int)floorf((w_start + 0.5f) * sw_scale - 0.5f); // -1 at left edge

    // ---- Issue hr_x loads early (latency hides under phases A/B).
    int w = w_start + tid;
    bool valid = (tid < TILE_W);
    size_t hr_row0 = ((size_t)b * HR_H + hbase) * (size_t)HR_W + w;
    float4 xr[ROWS];
#pragma unroll
    for (int j = 0; j < ROWS; ++j) {
        xr[j] = valid ? hr_x[hr_row0 + (size_t)j * HR_W]
                      : make_float4(0.f, 0.f, 0.f, 0.f);
    }

    // ---- Phase A: vertical 3-tap sums, RSETS x VCOLS = 192 tasks, one pass.
    if (tid < RSETS * VCOLS) {
        int rs = tid >> 6;                             // VCOLS = 64
        int cs = tid & 63;
        int ar = min(max(R0 + rs, 0), A_H - 1);        // A-row this set serves
        int col = min(max(c0 + cs, 0), LR_W - 1);      // lr col (clamped)
        const float4* px = lr_x + ((size_t)b * LR_H + ar) * LR_W + col;
        const float4* py = lr_y + ((size_t)b * LR_H + ar) * LR_W + col;
        float4 sx  = make_float4(0.f, 0.f, 0.f, 0.f);
        float4 sy  = make_float4(0.f, 0.f, 0.f, 0.f);
        float4 sxy = make_float4(0.f, 0.f, 0.f, 0.f);
        float4 sxx = make_float4(0.f, 0.f, 0.f, 0.f);
#pragma unroll
        for (int dy = 0; dy < 3; ++dy) {
            float4 x = px[(size_t)dy * LR_W];
            float4 y = py[(size_t)dy * LR_W];
            sx  = f4add(sx, x);
            sy  = f4add(sy, y);
            sxy = f4fma(x, y, sxy);
            sxx = f4fma(x, x, sxx);
        }
        vs[rs][0][cs] = sx;
        vs[rs][1][cs] = sy;
        vs[rs][2][cs] = sxy;
        vs[rs][3][cs] = sxx;
    }
    __syncthreads();

    // ---- Phase B: horizontal 3-tap -> A,b per rowset.
    // Map: wave w (=tid>>6) handles rowset w, lanes 0..ACOLS-1. 186 tasks, one pass.
    constexpr float inv9 = 1.0f / 9.0f;
    {
        int rs = tid >> 6;
        int sl = tid & 63;
        if (rs < RSETS && sl < ACOLS) {
            int a  = min(max(c0 + sl, 0), A_W - 1);  // A-col this slot represents
            int bs = a - c0;                          // slots bs..bs+2 hold cols a..a+2
            float4 hx  = f4add(f4add(vs[rs][0][bs], vs[rs][0][bs + 1]), vs[rs][0][bs + 2]);
            float4 hy  = f4add(f4add(vs[rs][1][bs], vs[rs][1][bs + 1]), vs[rs][1][bs + 2]);
            float4 hxy = f4add(f4add(vs[rs][2][bs], vs[rs][2][bs + 1]), vs[rs][2][bs + 2]);
            float4 hxx = f4add(f4add(vs[rs][3][bs], vs[rs][3][bs + 1]), vs[rs][3][bs + 2]);
            float4 mx  = f4scale(hx, inv9);
            float4 my  = f4scale(hy, inv9);
            float4 cov = f4sub(f4scale(hxy, inv9), f4mul(mx, my));
            float4 var = f4sub(f4scale(hxx, inv9), f4mul(mx, mx));
            float4 A = f4mul(cov, f4rcp(make_float4(var.x + EPS_F, var.y + EPS_F,
                                                    var.z + EPS_F, var.w + EPS_F)));
            float4 bb = f4sub(my, f4mul(A, mx));
            sA4[rs][sl] = A;
            sB4[rs][sl] = bb;
        }
    }
    __syncthreads();

    // ---- Phase C: horizontal lerp hoisted (tw, wi row-invariant).
    if (valid) {
        float sw = (w + 0.5f) * sw_scale - 0.5f;
        float fw = floorf(sw);
        float tw = sw - fw;
        int wi = min((int)fw - c0, ACOLS - 2);   // 0..60 for valid lanes

        float4 hA0 = f4lerp(sA4[0][wi], sA4[0][wi + 1], tw);
        float4 hB0 = f4lerp(sB4[0][wi], sB4[0][wi + 1], tw);
        float4 hA1 = f4lerp(sA4[1][wi], sA4[1][wi + 1], tw);
        float4 hB1 = f4lerp(sB4[1][wi], sB4[1][wi + 1], tw);
        float4 hA2 = f4lerp(sA4[2][wi], sA4[2][wi + 1], tw);
        float4 hB2 = f4lerp(sB4[2][wi], sB4[2][wi + 1], tw);

#pragma unroll
        for (int j = 0; j < ROWS; ++j) {
            // t in [0,2): tent weights over the 3 staged rowsets reproduce the
            // clamped vertical lerp exactly (slots hold clamped rows).
            float shj = (hbase + j + 0.5f) * sh_scale - 0.5f;
            float t = shj - (float)R0;
            float w0 = fmaxf(1.f - t, 0.f);
            float w1 = 1.f - fabsf(t - 1.f);
            float w2 = fmaxf(t - 1.f, 0.f);

            float4 aI = f4axpy(w2, hA2, f4axpy(w1, hA1, f4scale(hA0, w0)));
            float4 bI = f4axpy(w2, hB2, f4axpy(w1, hB1, f4scale(hB0, w0)));

            out[hr_row0 + (size_t)j * HR_W] = f4fma(aI, xr[j], bI);  // cached store
        }
    }
}

extern "C" void kernel_launch(void* const* d_in, const int* in_sizes, int n_in,
                              void* d_out, int out_size, void* d_ws, size_t ws_size,
                              hipStream_t stream) {
    const float4* lr_x = (const float4*)d_in[0];
    const float4* lr_y = (const float4*)d_in[1];
    const float4* hr_x = (const float4*)d_in[2];
    float4* out = (float4*)d_out;

    constexpr int nblocks = BATCH * ROWGRP * NTILES;   // 2 * 216 * 8 = 3456
    fgf_fused5<<<nblocks, 256, 0, stream>>>(lr_x, lr_y, hr_x, out);
}